// Round 6
// baseline (61.060 us; speedup 1.0000x reference)
//
#include <hip/hip_runtime.h>
#include <stdint.h>

// GGML Q8_0 fused dequant + GEMM:  out[16][8192] = x[16][8192] . W^T + bias
// HARNESS: quantized_weight arrives as int32, one GGML byte per element
// (zero-extended): 71,303,168 elems = 285.2 MB -> HBM-bound, ~45.3 us floor.
//
// R6 = R5 + T3/T4 counted-vmcnt pipeline:
//   triple-buffered chunks, prefetch depth 2, per-iteration barrier is
//   `s_waitcnt vmcnt(9)` + raw s_barrier + sched_barrier(0) -- chunk q+2's
//   9 per-wave gload_lds stay in flight across the barrier (never drain to 0
//   in the main loop). x-loads issue before the gload burst so the per-wave
//   vmcnt FIFO is [9 g(q+1)][2 x(q)][9 g(q+2)].
// Staging/dequant/MFMA identical to R5 (verified): width-4 global_load_lds,
// 274-dword LDS row stride (bank-balanced ds_read_b64), perm/xor/pk_add
// dequant, mfma_f32_16x16x32_f16 + f32 scale fixup, LDS cross-wave reduce.

typedef _Float16 half8   __attribute__((ext_vector_type(8)));
typedef _Float16 half2v  __attribute__((ext_vector_type(2)));
typedef float    float4v __attribute__((ext_vector_type(4)));
typedef uint2    __attribute__((may_alias)) u2a;
typedef float4v  __attribute__((may_alias)) f4a;

// two zero-extended quant bytes (.b0 of lo,hi) -> packed f16 pair == exact q
__device__ __forceinline__ uint32_t qpair(uint32_t lo, uint32_t hi) {
  uint32_t r = __builtin_amdgcn_perm(hi, lo, 0x0C040C00u); // [lo.b0,0,hi.b0,0]
  r ^= 0x64806480u;                                        // f16 1152+q each
  half2v v = __builtin_bit_cast(half2v, r);
  v = v + __builtin_bit_cast(half2v, (uint32_t)0xE480E480u); // -1152,-1152
  return __builtin_bit_cast(uint32_t, v);
}

__device__ __forceinline__ void gload4(const int* g, unsigned char* l) {
  __builtin_amdgcn_global_load_lds(
      (__attribute__((address_space(1))) void*)(void*)(const_cast<int*>(g)),
      (__attribute__((address_space(3))) void*)(void*)l,
      4, 0, 0);
}

// counted-vmcnt barrier: drain to N outstanding VMEM ops, then raw s_barrier.
// sched_barrier(0) fences compiler motion across it (rule #18).
#define PIPE_BARRIER(N) do {                                   \
    asm volatile("s_waitcnt vmcnt(" #N ")" ::: "memory");      \
    __builtin_amdgcn_s_barrier();                              \
    __builtin_amdgcn_sched_barrier(0);                         \
  } while (0)

extern "C" __global__ __launch_bounds__(512, 4)
void q8lin_kernel(const float* __restrict__ x,
                  const int* __restrict__ wq,
                  const float* __restrict__ bias,
                  float* __restrict__ out)
{
  // 3 chunk buffers x 18432 B + reduction buffer = 63.5 KB static LDS.
  __shared__ __align__(16) unsigned char lds[3][18432];
  __shared__ __align__(16) float red[8][16][16];

  const int tid  = threadIdx.x;
  const int wv   = tid >> 6;    // wave = chunk-local Q8 block index
  const int lane = tid & 63;
  const int c    = lane & 15;   // batch row (A) and weight row / out col (B)
  const int ksub = lane >> 4;   // k-subgroup within MFMA
  const int g    = blockIdx.x;  // output cols [g*16, g*16+16)

  // staging map: slot s = wv + 8t (t=0..8); flat dword f = s*64+lane;
  // row r = f/274, in-row dword u = f-274r (clamped into [0,272) data).
  const int* gptr[9];
  unsigned   lofs[9];
#pragma unroll
  for (int t = 0; t < 9; ++t) {
    unsigned s = (unsigned)(wv + 8 * t);
    unsigned f = s * 64u + (unsigned)lane;
    unsigned r = f / 274u; if (r > 15u) r = 15u;
    unsigned u = f - r * 274u; if (u > 271u) u = 271u;
    gptr[t] = wq + (size_t)((unsigned)g * 16u + r) * 8704u + u;
    lofs[t] = s * 256u;
  }

  const float*   xrow = x + (size_t)c * 8192 + (unsigned)wv * 32u
                          + (unsigned)ksub * 8u;
  const unsigned rb   = (unsigned)c * 1096u + 136u * (unsigned)wv;
  const unsigned qb   = rb + 8u + (unsigned)ksub * 32u;

  float4v acc = {0.f, 0.f, 0.f, 0.f};

  // prologue: chunks 0,1 in flight; drain chunk 0 only (9 stay outstanding)
#pragma unroll
  for (int t = 0; t < 9; ++t) gload4(gptr[t], &lds[0][0] + lofs[t]);
#pragma unroll
  for (int t = 0; t < 9; ++t) gload4(gptr[t] + 272, &lds[1][0] + lofs[t]);
  PIPE_BARRIER(9);

#pragma unroll 1
  for (int q = 0; q < 32; ++q) {
    // x loads FIRST in the VMEM FIFO for this iteration
    const float* xp = xrow + (size_t)q * 256;
    float4v f0 = *(const f4a*)xp;
    float4v f1 = *(const f4a*)(xp + 4);
    __builtin_amdgcn_sched_barrier(0);   // pin x-loads before the gload burst

    if (q < 30) {
      const unsigned b = (unsigned)(q + 2) % 3u;
      unsigned char* nxt = &lds[0][0] + b * 18432u;
      const int adv = (q + 2) * 272;
#pragma unroll
      for (int t = 0; t < 9; ++t) gload4(gptr[t] + adv, nxt + lofs[t]);
    }

    const unsigned char* cur = &lds[0][0] + ((unsigned)q % 3u) * 18432u;

    // scale: 2 int32 (bytes in .b0) at row byte 136*wv
    u2a s01 = *(const u2a*)(cur + rb);
    uint32_t sv = __builtin_amdgcn_perm(s01.y, s01.x, 0x0C0C0400u);
    const float dsc = (float)__builtin_bit_cast(_Float16, (uint16_t)sv);

    // quants: 8 int32 at row byte 136*wv + 8 + ksub*32 (bank-balanced b64s)
    u2a d0 = *(const u2a*)(cur + qb);
    u2a d1 = *(const u2a*)(cur + qb + 8);
    u2a d2 = *(const u2a*)(cur + qb + 16);
    u2a d3 = *(const u2a*)(cur + qb + 24);
    half8 bfrag;
    { union { half8 h; uint32_t u[4]; } ub;
      ub.u[0] = qpair(d0.x, d0.y);
      ub.u[1] = qpair(d1.x, d1.y);
      ub.u[2] = qpair(d2.x, d2.y);
      ub.u[3] = qpair(d3.x, d3.y);
      bfrag = ub.h; }

    // A fragment: x[c][q*256 + wv*32 + ksub*8 ..+8) as f16 RTZ (L2-resident)
    half8 afrag;
    { union { half8 h; uint32_t u[4]; } ua;
      ua.u[0] = __builtin_bit_cast(uint32_t, __builtin_amdgcn_cvt_pkrtz(f0[0], f0[1]));
      ua.u[1] = __builtin_bit_cast(uint32_t, __builtin_amdgcn_cvt_pkrtz(f0[2], f0[3]));
      ua.u[2] = __builtin_bit_cast(uint32_t, __builtin_amdgcn_cvt_pkrtz(f1[0], f1[1]));
      ua.u[3] = __builtin_bit_cast(uint32_t, __builtin_amdgcn_cvt_pkrtz(f1[2], f1[3]));
      afrag = ua.h; }

    float4v D = __builtin_amdgcn_mfma_f32_16x16x32_f16(
        afrag, bfrag, (float4v){0.f, 0.f, 0.f, 0.f}, 0, 0, 0);
    acc[0] = fmaf(dsc, D[0], acc[0]);
    acc[1] = fmaf(dsc, D[1], acc[1]);
    acc[2] = fmaf(dsc, D[2], acc[2]);
    acc[3] = fmaf(dsc, D[3], acc[3]);

    // barrier end-of-iter q: drain chunk q+1's loads, keep q+2's in flight.
    if (q < 30) { PIPE_BARRIER(9); } else { PIPE_BARRIER(0); }
  }

  // cross-wave K-reduction. C/D layout (m89): col=lane&15, row=(lane>>4)*4+r
  *(f4a*)(&red[wv][c][ksub * 4]) = acc;
  __syncthreads();

  if (tid < 256) {
    const int cc = tid & 15;
    const int rr = tid >> 4;
    float s = bias[g * 16 + cc];
#pragma unroll
    for (int w = 0; w < 8; ++w) s += red[w][cc][rr];
    out[(size_t)rr * 8192 + (size_t)(g * 16 + cc)] = s;
  }
}

extern "C" void kernel_launch(void* const* d_in, const int* in_sizes, int n_in,
                              void* d_out, int out_size, void* d_ws, size_t ws_size,
                              hipStream_t stream) {
  const float* x    = (const float*)d_in[0];
  const int*   wq   = (const int*)d_in[1];
  const float* bias = (const float*)d_in[2];
  float*       out  = (float*)d_out;
  (void)in_sizes; (void)n_in; (void)d_ws; (void)ws_size; (void)out_size;
  q8lin_kernel<<<dim3(8192 / 16), dim3(512), 0, stream>>>(x, wq, bias, out);
}

// Round 7
// 59.159 us; speedup vs baseline: 1.0321x; 1.0321x over previous
//
#include <hip/hip_runtime.h>
#include <stdint.h>

// GGML Q8_0 fused dequant + GEMM:  out[16][8192] = x[16][8192] . W^T + bias
// HARNESS: quantized_weight arrives as int32, one GGML byte per element
// (zero-extended): 71,303,168 elems = 285.2 MB -> HBM-bound, ~45.3 us floor.
//
// R7 = R5 structure with 2x run length:
//   chunk = 16 Q8 blocks/row (2176-B contiguous, 64-B-aligned runs per row;
//   perf across R3/R2/R5 tracked run length: 136B->79us, 272B->67, 1088B->56.7),
//   16 rounds (half the barriers), double-buffered dynamic LDS (78,336 B,
//   2 blocks/CU). LDS row stride 546 dwords: even (8-B-aligned b64 reads)
//   and 546%32==2 -> 16 rows on 16 distinct banks (conflict-free quant reads).
//   Wave wv consumes chunk-local Q8 blocks {wv, wv+8} (2 MFMAs/round).
// Staging/dequant/MFMA primitives identical to verified R5: width-4
// global_load_lds (uniform slot base), perm/xor/pk_add dequant,
// mfma_f32_16x16x32_f16 + f32 scale fixup, LDS cross-wave reduce.

typedef _Float16 half8   __attribute__((ext_vector_type(8)));
typedef _Float16 half2v  __attribute__((ext_vector_type(2)));
typedef float    float4v __attribute__((ext_vector_type(4)));
typedef uint2    __attribute__((may_alias)) u2a;
typedef float4v  __attribute__((may_alias)) f4a;

#define RSTRIDE_DW 546u      // LDS dwords per row image (544 data + 2 pad)
#define RSTRIDE_B  2184u     // bytes
#define CHUNK_DW   544u      // global dwords per row per chunk (16 Q8 blocks)
#define NSLOT      18        // staging slots per wave (clamped union covers 137)
#define BUFBYTES   35072u    // 137 slots * 256 B
#define REDOFF     70144u    // 2 * BUFBYTES
#define LDSBYTES   78336     // + 8 KiB reduction buffer

// two zero-extended quant bytes (.b0 of lo,hi) -> packed f16 pair == exact q
__device__ __forceinline__ uint32_t qpair(uint32_t lo, uint32_t hi) {
  uint32_t r = __builtin_amdgcn_perm(hi, lo, 0x0C040C00u); // [lo.b0,0,hi.b0,0]
  r ^= 0x64806480u;                                        // f16 1152+q each
  half2v v = __builtin_bit_cast(half2v, r);
  v = v + __builtin_bit_cast(half2v, (uint32_t)0xE480E480u); // -1152,-1152
  return __builtin_bit_cast(uint32_t, v);
}

__device__ __forceinline__ void gload4(const int* g, unsigned char* l) {
  __builtin_amdgcn_global_load_lds(
      (__attribute__((address_space(1))) void*)(void*)(const_cast<int*>(g)),
      (__attribute__((address_space(3))) void*)(void*)l,
      4, 0, 0);
}

extern "C" __global__ __launch_bounds__(512, 4)
void q8lin_kernel(const float* __restrict__ x,
                  const int* __restrict__ wq,
                  const float* __restrict__ bias,
                  float* __restrict__ out)
{
  extern __shared__ unsigned char lds[];

  const int tid  = threadIdx.x;
  const int wv   = tid >> 6;    // wave index
  const int lane = tid & 63;
  const int c    = lane & 15;   // batch row (A) and weight row / out col (B)
  const int ksub = lane >> 4;   // k-subgroup within MFMA
  const int g    = blockIdx.x;  // output cols [g*16, g*16+16)

  // staging map: slot s = min(wv + 8t, 136); flat dword f = s*64+lane;
  // row r = f/546 (clamp 15), in-row dword u = f-546r (clamp 543).
  // Slots >136 clamp to 136 -> benign duplicate writes (same data, L2-hit).
  unsigned gofs[NSLOT], lofs[NSLOT];
#pragma unroll
  for (int t = 0; t < NSLOT; ++t) {
    unsigned s = (unsigned)(wv + 8 * t); if (s > 136u) s = 136u;
    unsigned f = s * 64u + (unsigned)lane;
    unsigned r = f / RSTRIDE_DW; if (r > 15u) r = 15u;
    unsigned u = f - r * RSTRIDE_DW; if (u > 543u) u = 543u;
    gofs[t] = r * 8704u + u;   // dword offset within block's 16-row panel
    lofs[t] = s * 256u;        // uniform LDS slot base (builtin adds lane*4)
  }
  const int* panel = wq + (size_t)g * (16u * 8704u);

  const int      j1  = wv, j2 = wv + 8;         // chunk-local Q8 blocks
  const unsigned rb1 = RSTRIDE_B * (unsigned)c + 136u * (unsigned)j1;
  const unsigned rb2 = RSTRIDE_B * (unsigned)c + 136u * (unsigned)j2;
  const float*   xrow = x + (size_t)c * 8192 + (unsigned)ksub * 8u;

  float4v acc = {0.f, 0.f, 0.f, 0.f};

  // prologue: chunk 0
#pragma unroll
  for (int t = 0; t < NSLOT; ++t) gload4(panel + gofs[t], lds + lofs[t]);
  __syncthreads();

#pragma unroll 1
  for (int q = 0; q < 16; ++q) {
    if (q < 15) {
      unsigned char* nb  = lds + (unsigned)((q + 1) & 1) * BUFBYTES;
      const int*     src = panel + (unsigned)(q + 1) * CHUNK_DW;
#pragma unroll
      for (int t = 0; t < NSLOT; ++t) gload4(src + gofs[t], nb + lofs[t]);
    }
    const unsigned char* cur = lds + (unsigned)(q & 1) * BUFBYTES;

#pragma unroll
    for (int jj = 0; jj < 2; ++jj) {
      const unsigned rb = jj ? rb2 : rb1;
      const int      j  = jj ? j2 : j1;

      // fp16 scale from zero-extended dwords u=0,1 of block j
      u2a s01 = *(const u2a*)(cur + rb);
      uint32_t sv = __builtin_amdgcn_perm(s01.y, s01.x, 0x0C0C0400u);
      const float dsc = (float)__builtin_bit_cast(_Float16, (uint16_t)sv);

      // 8 quants for this lane: dwords u = 2 + 8*ksub .. +7 (8-B aligned b64s)
      const unsigned qb = rb + 8u + 32u * (unsigned)ksub;
      u2a d0 = *(const u2a*)(cur + qb);
      u2a d1 = *(const u2a*)(cur + qb + 8);
      u2a d2 = *(const u2a*)(cur + qb + 16);
      u2a d3 = *(const u2a*)(cur + qb + 24);
      half8 bfrag;
      { union { half8 h; uint32_t u[4]; } ub;
        ub.u[0] = qpair(d0.x, d0.y);
        ub.u[1] = qpair(d1.x, d1.y);
        ub.u[2] = qpair(d2.x, d2.y);
        ub.u[3] = qpair(d3.x, d3.y);
        bfrag = ub.h; }

      // A fragment: x[c][q*512 + j*32 + ksub*8 ..+8) as f16 RTZ (L2-resident)
      const float* xp = xrow + (size_t)q * 512 + (unsigned)j * 32u;
      float4v f0 = *(const f4a*)xp;
      float4v f1 = *(const f4a*)(xp + 4);
      half8 afrag;
      { union { half8 h; uint32_t u[4]; } ua;
        ua.u[0] = __builtin_bit_cast(uint32_t, __builtin_amdgcn_cvt_pkrtz(f0[0], f0[1]));
        ua.u[1] = __builtin_bit_cast(uint32_t, __builtin_amdgcn_cvt_pkrtz(f0[2], f0[3]));
        ua.u[2] = __builtin_bit_cast(uint32_t, __builtin_amdgcn_cvt_pkrtz(f1[0], f1[1]));
        ua.u[3] = __builtin_bit_cast(uint32_t, __builtin_amdgcn_cvt_pkrtz(f1[2], f1[3]));
        afrag = ua.h; }

      float4v D = __builtin_amdgcn_mfma_f32_16x16x32_f16(
          afrag, bfrag, (float4v){0.f, 0.f, 0.f, 0.f}, 0, 0, 0);
      acc[0] = fmaf(dsc, D[0], acc[0]);
      acc[1] = fmaf(dsc, D[1], acc[1]);
      acc[2] = fmaf(dsc, D[2], acc[2]);
      acc[3] = fmaf(dsc, D[3], acc[3]);
    }

    __syncthreads();  // next buffer staged; cur free for overwrite
  }

  // cross-wave K-reduction. C/D layout (m89): col=lane&15, row=(lane>>4)*4+r
  float (*red)[16][16] = (float (*)[16][16])(lds + REDOFF);
  *(f4a*)(&red[wv][c][ksub * 4]) = acc;
  __syncthreads();

  if (tid < 256) {
    const int cc = tid & 15;
    const int rr = tid >> 4;
    float s = bias[g * 16 + cc];
#pragma unroll
    for (int w = 0; w < 8; ++w) s += red[w][cc][rr];
    out[(size_t)rr * 8192 + (size_t)(g * 16 + cc)] = s;
  }
}

extern "C" void kernel_launch(void* const* d_in, const int* in_sizes, int n_in,
                              void* d_out, int out_size, void* d_ws, size_t ws_size,
                              hipStream_t stream) {
  const float* x    = (const float*)d_in[0];
  const int*   wq   = (const int*)d_in[1];
  const float* bias = (const float*)d_in[2];
  float*       out  = (float*)d_out;
  (void)in_sizes; (void)n_in; (void)d_ws; (void)ws_size; (void)out_size;
  hipFuncSetAttribute((const void*)q8lin_kernel,
                      hipFuncAttributeMaxDynamicSharedMemorySize, LDSBYTES);
  q8lin_kernel<<<dim3(8192 / 16), dim3(512), LDSBYTES, stream>>>(x, wq, bias, out);
}